// Round 5
// baseline (385.518 us; speedup 1.0000x reference)
//
#include <hip/hip_runtime.h>
#include <hip/hip_bf16.h>

// Problem constants
#define N_  4
#define C_  256
#define K_  16
#define T_  16
#define H_  56
#define W_  56
#define HW_ (H_ * W_)          // 3136
#define THW_ (T_ * HW_)        // 50176
#define TP_ 8
#define HP_ 28
#define WP_ 28
#define PP_ (HP_ * WP_)        // 784

// ---------------------------------------------------------------------------
// Kernel 1: emap[n,t,h,w] = exp( max_k( sum_c w[n,k,c]*vw[n,c,t,h,w] ) / 16 )
// Block = 256 thr = 4 waves covering 256 positions; each wave independently
// does 64 positions x all 256 channels. Channel split is INSIDE the wave:
// lane&3 = 64-channel quarter, lane>>2 = float4 position group. Cross-quarter
// reduction = two __shfl_xor (DPP) -> no partial-sum LDS, no barriers after
// w staging. w[n] staged transposed in LDS (wt[c][k], b128 broadcast reads).
// ---------------------------------------------------------------------------
__global__ __launch_bounds__(256) void emap_kernel(const float* __restrict__ vw,
                                                   const float* __restrict__ w,
                                                   float* __restrict__ emap) {
    __shared__ float wt[C_ * K_];           // 16 KB, wt[c*16+k] = w[n][k][c]
    const int tid  = threadIdx.x;
    const int lane = tid & 63;
    const int wv   = tid >> 6;
    const int q    = lane & 3;              // channel quarter
    const int j    = lane >> 2;             // position group (0..15)
    const int bpn  = THW_ / 256;            // 196 blocks per n
    const int n    = blockIdx.x / bpn;
    const int s0   = (blockIdx.x % bpn) * 256;

    const float* wn = w + n * (K_ * C_);
#pragma unroll
    for (int k = 0; k < K_; ++k) wt[tid * K_ + k] = wn[k * C_ + tid];
    __syncthreads();

    const float* vb = vw + (long)(n * C_ + q * 64) * THW_ + s0 + wv * 64 + 4 * j;

    float a[K_][4];
#pragma unroll
    for (int k = 0; k < K_; ++k)
#pragma unroll
        for (int p = 0; p < 4; ++p) a[k][p] = 0.f;

#pragma unroll 8
    for (int g = 0; g < 64; ++g) {
        const float4 v = *(const float4*)(vb + (long)g * THW_);
        const float* wc = &wt[(q * 64 + g) * K_];
#pragma unroll
        for (int kk = 0; kk < 4; ++kk) {
            const float4 wk = *(const float4*)&wc[kk * 4];
#define FMA4(Q, WC) \
            a[kk*4+Q][0] += (WC) * v.x; a[kk*4+Q][1] += (WC) * v.y; \
            a[kk*4+Q][2] += (WC) * v.z; a[kk*4+Q][3] += (WC) * v.w;
            FMA4(0, wk.x) FMA4(1, wk.y) FMA4(2, wk.z) FMA4(3, wk.w)
#undef FMA4
        }
    }

    // butterfly sum across the 4 channel quarters (lanes q^1, q^2)
#pragma unroll
    for (int k = 0; k < K_; ++k)
#pragma unroll
        for (int p = 0; p < 4; ++p) {
            float t = a[k][p];
            t += __shfl_xor(t, 1);
            t += __shfl_xor(t, 2);
            a[k][p] = t;
        }

    // each lane finalizes position (j*4 + q): select component q, max over k
    float m = -3.4e38f;
#pragma unroll
    for (int k = 0; k < K_; ++k) {
        const float v01 = (q & 1) ? a[k][1] : a[k][0];
        const float v23 = (q & 1) ? a[k][3] : a[k][2];
        const float v   = (q & 2) ? v23 : v01;
        m = fmaxf(m, v);
    }
    emap[(long)n * THW_ + s0 + wv * 64 + lane] = expf(m * 0.0625f);
}

// ---------------------------------------------------------------------------
// Kernel 2: rden[n,tp,h',w'] = 1 / boxsum3x3x3(emap). Tiny; emap L2-resident.
// ---------------------------------------------------------------------------
__global__ __launch_bounds__(256) void rden_kernel(const float* __restrict__ emap,
                                                   float* __restrict__ rden) {
    const int gid = blockIdx.x * 256 + threadIdx.x;   // [0, 25088)
    const int n   = gid / (TP_ * PP_);
    const int r   = gid % (TP_ * PP_);
    const int tp  = r / PP_;
    const int p   = r % PP_;
    const int hp  = p / WP_, wp = p % WP_;
    const int t0  = 2 * tp - 1, h0 = 2 * hp - 1, w0 = 2 * wp - 1;
    const float* eb = emap + (long)n * THW_;

    float den = 0.f;
#pragma unroll
    for (int dt = 0; dt < 3; ++dt) {
        const int tt = t0 + dt;
        const bool tv = (tt >= 0);
        const int tc = tv ? tt : 0;
#pragma unroll
        for (int dh = 0; dh < 3; ++dh) {
            const int h = h0 + dh;
            const bool hv = tv && (h >= 0);
            const int hc = (h >= 0) ? h : 0;
#pragma unroll
            for (int dw = 0; dw < 3; ++dw) {
                const int w = w0 + dw;
                const bool v = hv && (w >= 0);
                const int wc = (w >= 0) ? w : 0;
                const float ev = eb[tc * HW_ + hc * W_ + wc];
                den += v ? ev : 0.f;
            }
        }
    }
    rden[gid] = 1.0f / den;
}

static __device__ __forceinline__ float4 mul4(float4 a, float4 b) {
    return make_float4(a.x * b.x, a.y * b.y, a.z * b.z, a.w * b.w);
}

// ---------------------------------------------------------------------------
// Kernel 3: block = (c, n), rolling window over t'. Product p = vw*emap kept
// in a 4-slot LDS ring (slot = t & 3; slot 3 pre-zeroed serves t = -1).
// Each vw slice is read from HBM exactly ONCE. Staging for t'+1 is split:
// global->reg loads issued BEFORE the compute phase (latency hidden under
// the 27-tap gather), ds_write after the barrier (T14 async-stage).
// Taps are aligned float2-pair + clamped float1 LDS reads (2-way = free).
// ---------------------------------------------------------------------------
__global__ __launch_bounds__(256) void box_kernel(const float* __restrict__ vw,
                                                  const float* __restrict__ emap,
                                                  const float* __restrict__ rden,
                                                  float* __restrict__ out) {
    __shared__ float sp[4][HW_];     // 50176 B

    const int tid = threadIdx.x;
    const int c   = blockIdx.x;
    const int n   = blockIdx.y;
    const float* vb = vw + ((long)(n * C_ + c)) * THW_;
    const float* eb = emap + (long)n * THW_;
    float* ob = out + ((long)(n * C_ + c)) * (TP_ * PP_);
    const float* rb = rden + n * (TP_ * PP_);

    // zero slot 3 (t = -1); stage t=0 -> slot0, t=1 -> slot1
    {
        float4* z = (float4*)sp[3];
        for (int i = tid; i < HW_ / 4; i += 256) z[i] = make_float4(0.f, 0.f, 0.f, 0.f);
#pragma unroll
        for (int sl = 0; sl < 2; ++sl) {
            const float4* vs = (const float4*)(vb + sl * HW_);
            const float4* es = (const float4*)(eb + sl * HW_);
            float4* d = (float4*)sp[sl];
            for (int i = tid; i < HW_ / 4; i += 256) d[i] = mul4(vs[i], es[i]);
        }
    }
    __syncthreads();

    for (int tp = 0; tp < TP_; ++tp) {
        // ---- issue prefetch loads for t = 2tp+2, 2tp+3 (registers only) ----
        const int tA = 2 * tp + 2;
        const bool pf = (tA < T_);
        float4 pv0, pv1, pv2, pe0, pe1, pe2;
        float4 qv0, qv1, qv2, qe0, qe1, qe2;
        if (pf) {
            const float4* vA = (const float4*)(vb + tA * HW_);
            const float4* eA = (const float4*)(eb + tA * HW_);
            const float4* vB = (const float4*)(vb + (tA + 1) * HW_);
            const float4* eB = (const float4*)(eb + (tA + 1) * HW_);
            pv0 = vA[tid]; pv1 = vA[tid + 256]; pv2 = vA[tid + 512];
            pe0 = eA[tid]; pe1 = eA[tid + 256]; pe2 = eA[tid + 512];
            qv0 = vB[tid]; qv1 = vB[tid + 256]; qv2 = vB[tid + 512];
            qe0 = eB[tid]; qe1 = eB[tid + 256]; qe2 = eB[tid + 512];
        }

        // ---- compute t' = tp from slots {2tp-1, 2tp, 2tp+1} ----
        const float* sA = sp[(2 * tp + 3) & 3];   // t = 2tp-1 (slot3 = zeros at tp=0)
        const float* sB = sp[(2 * tp) & 3];
        const float* sC = sp[(2 * tp + 1) & 3];
        const float* rt = rb + tp * PP_;
        float* ot = ob + tp * PP_;
        for (int p = tid; p < PP_; p += 256) {
            const int hp = p / WP_, wp = p % WP_;
            const int h0 = 2 * hp - 1;
            const int wE = 2 * wp;                      // aligned pair (w0+1, w0+2)
            const int wO = (wp > 0) ? (2 * wp - 1) : 0; // clamped w0
            float num = 0.f;
#pragma unroll
            for (int dh = 0; dh < 3; ++dh) {
                const int h = h0 + dh;
                const int base = ((h >= 0) ? h : 0) * W_;
                const float e0 = sA[base + wO] + sB[base + wO] + sC[base + wO];
                const float2 a2 = *(const float2*)&sA[base + wE];
                const float2 b2 = *(const float2*)&sB[base + wE];
                const float2 c2 = *(const float2*)&sC[base + wE];
                float row = a2.x + a2.y + b2.x + b2.y + c2.x + c2.y;
                row += (wp > 0) ? e0 : 0.f;
                num += (h >= 0) ? row : 0.f;
            }
            ot[p] = num * rt[p];
        }
        __syncthreads();

        // ---- write prefetched slices into their slots ----
        if (pf) {
            float4* dA = (float4*)sp[tA & 3];
            float4* dB = (float4*)sp[(tA + 1) & 3];
            dA[tid]       = mul4(pv0, pe0);
            dA[tid + 256] = mul4(pv1, pe1);
            dA[tid + 512] = mul4(pv2, pe2);
            dB[tid]       = mul4(qv0, qe0);
            dB[tid + 256] = mul4(qv1, qe1);
            dB[tid + 512] = mul4(qv2, qe2);
            if (tid < 16) {   // tail float4 chunks 768..783
                const float4* vA = (const float4*)(vb + tA * HW_);
                const float4* eA = (const float4*)(eb + tA * HW_);
                const float4* vB = (const float4*)(vb + (tA + 1) * HW_);
                const float4* eB = (const float4*)(eb + (tA + 1) * HW_);
                dA[768 + tid] = mul4(vA[768 + tid], eA[768 + tid]);
                dB[768 + tid] = mul4(vB[768 + tid], eB[768 + tid]);
            }
        }
        __syncthreads();
    }
}

extern "C" void kernel_launch(void* const* d_in, const int* in_sizes, int n_in,
                              void* d_out, int out_size, void* d_ws, size_t ws_size,
                              hipStream_t stream) {
    const float* vw = (const float*)d_in[0];
    const float* w  = (const float*)d_in[1];
    float* out  = (float*)d_out;
    float* emap = (float*)d_ws;                 // 802816 B
    float* rden = emap + (long)N_ * THW_;       // 100352 B

    // Kernel 1: 784 blocks (196 per n)
    emap_kernel<<<784, 256, 0, stream>>>(vw, w, emap);

    // Kernel 2: 98 blocks
    rden_kernel<<<98, 256, 0, stream>>>(emap, rden);

    // Kernel 3: grid (c=256, n=4) = 1024 blocks, vw read exactly once
    box_kernel<<<dim3(C_, N_), 256, 0, stream>>>(vw, emap, rden, out);
}